// Round 1
// 123.633 us; speedup vs baseline: 1.0005x; 1.0005x over previous
//
#include <hip/hip_runtime.h>
#include <math.h>

#define H 768
#define L 256
#define NB 4
#define NL 13

typedef _Float16 h2 __attribute__((ext_vector_type(2)));
typedef _Float16 h4 __attribute__((ext_vector_type(4)));
typedef _Float16 half8 __attribute__((ext_vector_type(8)));
typedef float f32x4 __attribute__((ext_vector_type(4)));

// Packed-fp16 GELU, u-space poly (11 pk ops incl. caller's input add).
// erf(x/sqrt2) ~= xc*P(u), u=xc*xc, xc=clamp(x,+-3.75).
// NOTE: numerics byte-identical to the verified version — absmax sits at the
// 0.0039 threshold, no margin for coefficient restructuring.
__device__ inline h2 gelu_pk(h2 x) {
    const _Float16 kC = (_Float16)3.75f;
    h2 hi = {kC, kC}, lo = {(_Float16)-3.75f, (_Float16)-3.75f};
    h2 xc = __builtin_elementwise_min(__builtin_elementwise_max(x, lo), hi);
    h2 u = xc * xc;
    const _Float16 d4v = (_Float16)2.0333e-5f,  d3v = (_Float16)-0.00084672f;
    const _Float16 d2v = (_Float16)0.0140002f,  d1v = (_Float16)-0.1234557f;
    const _Float16 d0v = (_Float16)0.7946463f;
    h2 d4 = {d4v, d4v}, d3 = {d3v, d3v}, d2 = {d2v, d2v}, d1 = {d1v, d1v}, d0 = {d0v, d0v};
    h2 p = u * (u * (u * (u * d4 + d3) + d2) + d1) + d0;   // v_pk_fma_f16 chain
    h2 t = xc * p;
    h2 w = x * t + x;                       // x*(1+t) via pk fma
    const _Float16 kH = (_Float16)0.5f;
    h2 halfv = {kH, kH};
    return w * halfv;
}

// ---------------- Kernel 1: fused prep GEMM, v2 ------------------------------
// 32x64 tiles -> 768 blocks (3 blocks/CU vs 1.56 before), double-buffered LDS,
// register-staged prefetch of tile k+1 issued before MFMAs of tile k,
// ONE barrier per K-step. Fragment/pack layout identical to proven version.
__global__ __launch_bounds__(256) void gemm_fused(
    const float* __restrict__ X, const float* __restrict__ W1,
    const float* __restrict__ b1, const float* __restrict__ W2,
    _Float16* __restrict__ Pxs2, _Float16* __restrict__ Pxe,
    _Float16* __restrict__ Bfrag2)
{
    const int tid = threadIdx.x;

    if (blockIdx.x >= 768) {                     // W2 repack (16 blocks)
        int base = (blockIdx.x - 768) * 768 + tid;
        #pragma unroll
        for (int r = 0; r < 3; ++r) {
            int idx = base + r * 256;            // < 12288
            int u = idx & 7;
            int lane = (idx >> 3) & 63;
            int kb = idx >> 9;
            int k = kb * 32 + ((lane >> 4) << 3) + u;
            int nn = lane & 15;
            float v = (nn < NL) ? W2[(size_t)k * NL + nn] : 0.f;
            Bfrag2[idx] = (_Float16)v;
        }
        return;
    }

    __shared__ _Float16 As[2][32][72];           // [buf][m][k-local]
    __shared__ _Float16 Bs[2][64][72];           // [buf][n][k-local]

    const int w = tid >> 6, lane = tid & 63;
    const int ln = lane & 15, quad = lane >> 4;
    const int bm = blockIdx.x & 31;              // consecutive blocks share bn ->
    const int bn = blockIdx.x >> 5;              // W1 panel stays hot in L2
    const int m0 = bm * 32;
    const int n0g = bn * 64;                     // n' in [0,1536)
    const bool isE = (n0g >= H);
    const float* Wb = W1 + (isE ? (size_t)H * H : 0);
    const int c0 = isE ? (n0g - H) : n0g;

    const int ar = tid >> 4;                     // 0..15
    const int ac = (tid & 15) * 4;

    float4 fA0, fA1, fB0a, fB0b, fB1a, fB1b;

#define G_LOAD(KR) do { \
    const int k0_ = (KR) * 64; \
    fA0 = *(const float4*)&X[(size_t)(m0 + ar) * H + k0_ + ac]; \
    fA1 = *(const float4*)&X[(size_t)(m0 + 16 + ar) * H + k0_ + ac]; \
    const float* wr0_ = &Wb[(size_t)(k0_ + 2 * ar) * H + c0 + ac]; \
    fB0a = *(const float4*)wr0_; \
    fB0b = *(const float4*)(wr0_ + H); \
    const float* wr1_ = &Wb[(size_t)(k0_ + 2 * (16 + ar)) * H + c0 + ac]; \
    fB1a = *(const float4*)wr1_; \
    fB1b = *(const float4*)(wr1_ + H); \
} while (0)

#define L_STORE(BUF) do { \
    h4 oa0 = { (_Float16)fA0.x, (_Float16)fA0.y, (_Float16)fA0.z, (_Float16)fA0.w }; \
    h4 oa1 = { (_Float16)fA1.x, (_Float16)fA1.y, (_Float16)fA1.z, (_Float16)fA1.w }; \
    *(h4*)&As[BUF][ar][ac] = oa0; \
    *(h4*)&As[BUF][16 + ar][ac] = oa1; \
    h2 p0 = {(_Float16)fB0a.x, (_Float16)fB0b.x}; \
    h2 p1 = {(_Float16)fB0a.y, (_Float16)fB0b.y}; \
    h2 p2 = {(_Float16)fB0a.z, (_Float16)fB0b.z}; \
    h2 p3 = {(_Float16)fB0a.w, (_Float16)fB0b.w}; \
    *(h2*)&Bs[BUF][ac + 0][2 * ar] = p0; \
    *(h2*)&Bs[BUF][ac + 1][2 * ar] = p1; \
    *(h2*)&Bs[BUF][ac + 2][2 * ar] = p2; \
    *(h2*)&Bs[BUF][ac + 3][2 * ar] = p3; \
    h2 q0 = {(_Float16)fB1a.x, (_Float16)fB1b.x}; \
    h2 q1 = {(_Float16)fB1a.y, (_Float16)fB1b.y}; \
    h2 q2 = {(_Float16)fB1a.z, (_Float16)fB1b.z}; \
    h2 q3 = {(_Float16)fB1a.w, (_Float16)fB1b.w}; \
    *(h2*)&Bs[BUF][ac + 0][2 * (16 + ar)] = q0; \
    *(h2*)&Bs[BUF][ac + 1][2 * (16 + ar)] = q1; \
    *(h2*)&Bs[BUF][ac + 2][2 * (16 + ar)] = q2; \
    *(h2*)&Bs[BUF][ac + 3][2 * (16 + ar)] = q3; \
} while (0)

    const int wm = w & 1, wn = w >> 1;           // wave tile: 16m x 32n
    f32x4 acc[2] = {};

    G_LOAD(0);
    L_STORE(0);
    __syncthreads();

    for (int kr = 0; kr < 12; ++kr) {
        const int cur = kr & 1;
        if (kr < 11) G_LOAD(kr + 1);             // prefetch next tile into regs
        #pragma unroll
        for (int sub = 0; sub < 2; ++sub) {
            const int ko = sub * 32 + quad * 8;
            half8 a   = *(const half8*)&As[cur][wm * 16 + ln][ko];
            half8 b0  = *(const half8*)&Bs[cur][wn * 32 + ln][ko];
            half8 b1f = *(const half8*)&Bs[cur][wn * 32 + 16 + ln][ko];
            acc[0] = __builtin_amdgcn_mfma_f32_16x16x32_f16(a, b0,  acc[0], 0, 0, 0);
            acc[1] = __builtin_amdgcn_mfma_f32_16x16x32_f16(a, b1f, acc[1], 0, 0, 0);
        }
        if (kr < 11) L_STORE(cur ^ 1);           // write OTHER buffer (no race)
        __syncthreads();                         // one barrier per K-step
    }

    const int mb = m0 + wm * 16 + quad * 4;      // C/D: col=ln, row=quad*4+r
    const int nb = wn * 32;
    if (!isE) {
        float bv0 = b1[n0g + nb + ln];
        float bv1 = b1[n0g + nb + 16 + ln];
        #pragma unroll
        for (int r = 0; r < 4; ++r) {
            Pxs2[(size_t)(mb + r) * H + (n0g + nb + ln)]      = (_Float16)(acc[0][r] + bv0);
            Pxs2[(size_t)(mb + r) * H + (n0g + nb + 16 + ln)] = (_Float16)(acc[1][r] + bv1);
        }
    } else {
        #pragma unroll
        for (int r = 0; r < 4; ++r) {
            Pxe[(size_t)(mb + r) * H + (c0 + nb + ln)]      = (_Float16)acc[0][r];
            Pxe[(size_t)(mb + r) * H + (c0 + nb + 16 + ln)] = (_Float16)acc[1][r];
        }
    }
#undef G_LOAD
#undef L_STORE
}

// ---------------- Kernel 2: span v6 ------------------------------------------
// K-split occupancy doubling: grid 2048, block = 4 i-rows x 32 j. Wave (jh,kh):
// jh picks 16 j, kh picks K-half (kb 0..11 / 12..23). 8192 waves = 32 waves/CU
// (was 16) with UNCHANGED total xe/bfrag L2 traffic. f32 reduce via LDS.
// bfrag now distance-2 register-prefetched like xe (removes per-group L2 stall).
__global__ __launch_bounds__(256, 6) void span_mfma_kernel(
    const _Float16* __restrict__ Pxs2, const _Float16* __restrict__ Pxe,
    const _Float16* __restrict__ Bfrag2, const float* __restrict__ b2,
    float* __restrict__ out)
{
    __shared__ unsigned int xsf[4 * H / 2];      // four i-rows of fp16 pairs (6 KB)
    __shared__ f32x4 redbuf[2][4][64];           // [jh][i01][lane] (8 KB)
    const int ip = blockIdx.x >> 3;              // 0..255
    const int jq = blockIdx.x & 7;               // 0..7 (32 j per block)
    const int bi0 = ip * 4;                      // b*L + i (quad start; same b)
    const int b = bi0 >> 8;
    const int tid = threadIdx.x;

    const unsigned int* xsrc = (const unsigned int*)(Pxs2 + (size_t)bi0 * H);
    #pragma unroll
    for (int t = 0; t < 6; ++t) xsf[t * 256 + tid] = xsrc[t * 256 + tid];

    const int w = tid >> 6;
    const int lane = tid & 63;
    const int jh = w & 1;                        // which 16-j half
    const int kh = w >> 1;                       // which K half
    const int n = lane & 15;
    const int quad = lane >> 4;
    const int j_load = jq * 32 + jh * 16 + n;    // A-frag row m = lane&15

    const int kb0 = kh * 12;
    const int kbe = kb0 + 12;

    const _Float16* xerow = Pxe + (size_t)(b * L + j_load) * H + quad * 8;
    const half8* bptr = (const half8*)(Bfrag2 + (size_t)lane * 8);

    f32x4 acc[4] = {};
    __syncthreads();

    uint4 xe0 = *(const uint4*)(xerow + kb0 * 32);          // kb0
    uint4 xe1 = *(const uint4*)(xerow + (kb0 + 1) * 32);    // kb0+1
    uint4 bf0 = *(const uint4*)(bptr + (size_t)kb0 * 64);
    uint4 bf1 = *(const uint4*)(bptr + (size_t)(kb0 + 1) * 64);

    #pragma unroll 3
    for (int kb = kb0; kb < kbe; ++kb) {
        uint4 xecur = xe0;  xe0 = xe1;
        uint4 bfcur = bf0;  bf0 = bf1;
        if (kb + 2 < kbe) {                      // wave-uniform
            xe1 = *(const uint4*)(xerow + (kb + 2) * 32);
            bf1 = *(const uint4*)(bptr + (size_t)(kb + 2) * 64);
        }

        half8 bfrag = __builtin_bit_cast(half8, bfcur);
        h2 xep[4] = { __builtin_bit_cast(h2, xecur.x), __builtin_bit_cast(h2, xecur.y),
                      __builtin_bit_cast(h2, xecur.z), __builtin_bit_cast(h2, xecur.w) };
        const int xo = kb * 16 + quad * 4;       // uint index of lane's 8 fp16

        #pragma unroll
        for (int i01 = 0; i01 < 4; ++i01) {
            uint4 xsd = *(const uint4*)&xsf[i01 * (H / 2) + xo];
            h2 xsp[4] = { __builtin_bit_cast(h2, xsd.x), __builtin_bit_cast(h2, xsd.y),
                          __builtin_bit_cast(h2, xsd.z), __builtin_bit_cast(h2, xsd.w) };
            unsigned int pk[4];
            #pragma unroll
            for (int p = 0; p < 4; ++p) {
                h2 g = gelu_pk(xsp[p] + xep[p]);
                pk[p] = __builtin_bit_cast(unsigned int, g);
            }
            uint4 pk4 = {pk[0], pk[1], pk[2], pk[3]};
            half8 afrag = __builtin_bit_cast(half8, pk4);
            acc[i01] = __builtin_amdgcn_mfma_f32_16x16x32_f16(afrag, bfrag, acc[i01], 0, 0, 0);
        }
    }

    // cross-wave K reduce: kh=1 publishes, kh=0 sums + stores
    if (kh == 1) {
        #pragma unroll
        for (int i01 = 0; i01 < 4; ++i01) redbuf[jh][i01][lane] = acc[i01];
    }
    __syncthreads();

    // C/D: col = lane&15 = label n, row = quad*4 + r = j-offset in the m-tile
    if (kh == 0 && n < NL) {
        float b2v = b2[n];
        #pragma unroll
        for (int i01 = 0; i01 < 4; ++i01) {
            f32x4 r2 = redbuf[jh][i01][lane];
            #pragma unroll
            for (int r = 0; r < 4; ++r) {
                int j = jq * 32 + jh * 16 + quad * 4 + r;
                out[((size_t)(bi0 + i01) * L + j) * NL + n] = acc[i01][r] + r2[r] + b2v;
            }
        }
    }
}

// ---------------- Launch ------------------------------------------------------
extern "C" void kernel_launch(void* const* d_in, const int* in_sizes, int n_in,
                              void* d_out, int out_size, void* d_ws, size_t ws_size,
                              hipStream_t stream)
{
    (void)in_sizes; (void)n_in; (void)out_size; (void)ws_size;
    const float* X  = (const float*)d_in[0];
    const float* W1 = (const float*)d_in[1];
    const float* b1 = (const float*)d_in[2];
    const float* W2 = (const float*)d_in[3];
    const float* b2 = (const float*)d_in[4];
    float* out = (float*)d_out;

    char* ws = (char*)d_ws;
    _Float16* Pxs2   = (_Float16*)ws;                          // 1.5 MB
    _Float16* Pxe    = Pxs2 + (size_t)NB * L * H;              // 1.5 MB
    _Float16* Bfrag2 = Pxe + (size_t)NB * L * H;               // 24 KB

    gemm_fused<<<dim3(784), 256, 0, stream>>>(X, W1, b1, W2, Pxs2, Pxe, Bfrag2);
    span_mfma_kernel<<<dim3(2048), 256, 0, stream>>>(Pxs2, Pxe, Bfrag2, b2, out);
}

// Round 2
// 123.225 us; speedup vs baseline: 1.0038x; 1.0033x over previous
//
#include <hip/hip_runtime.h>
#include <math.h>

#define H 768
#define L 256
#define NB 4
#define NL 13

typedef _Float16 h2 __attribute__((ext_vector_type(2)));
typedef _Float16 h4 __attribute__((ext_vector_type(4)));
typedef _Float16 half8 __attribute__((ext_vector_type(8)));
typedef float f32x4 __attribute__((ext_vector_type(4)));

// Packed-fp16 GELU as ONE pinned inline-asm block: exactly 11 v_pk_* ops,
// byte-identical numerics to the verified builtin version (same ops, same
// order, same constants). Constants arrive as laundered VGPRs (see launder8)
// so the compiler can neither rematerialize them per call nor scalarize the
// min/max. This is the fix for the observed 2x VALU instruction bloat
// (36M instrs vs 17.3M GELU floor; VALUBusy 62% @ 47us, MfmaUtil 5%).
__device__ inline unsigned int gelu_asm(
    unsigned int xs, unsigned int xe,
    unsigned int lo, unsigned int hi,
    unsigned int d4, unsigned int d3, unsigned int d2, unsigned int d1,
    unsigned int d0, unsigned int hf)
{
    unsigned int x, xc, u, p;
    asm("v_pk_add_f16 %0, %4, %5\n\t"   // x  = xs + xe
        "v_pk_max_f16 %1, %0, %6\n\t"   // xc = max(x, -3.75)
        "v_pk_min_f16 %1, %1, %7\n\t"   // xc = min(xc, 3.75)
        "v_pk_mul_f16 %2, %1, %1\n\t"   // u  = xc*xc
        "v_pk_fma_f16 %3, %2, %8, %9\n\t"   // p = u*d4 + d3
        "v_pk_fma_f16 %3, %2, %3, %10\n\t"  // p = u*p + d2
        "v_pk_fma_f16 %3, %2, %3, %11\n\t"  // p = u*p + d1
        "v_pk_fma_f16 %3, %2, %3, %12\n\t"  // p = u*p + d0
        "v_pk_mul_f16 %3, %1, %3\n\t"   // t = xc*p
        "v_pk_fma_f16 %3, %0, %3, %0\n\t"   // w = x*t + x
        "v_pk_mul_f16 %0, %3, %13"      // out = w*0.5
        : "=&v"(x), "=&v"(xc), "=&v"(u), "=&v"(p)
        : "v"(xs), "v"(xe), "v"(lo), "v"(hi), "v"(d4), "v"(d3),
          "v"(d2), "v"(d1), "v"(d0), "v"(hf));
    return x;
}

__device__ inline unsigned int h2const(float f) {
    _Float16 c = (_Float16)f;
    h2 r = {c, c};
    return __builtin_bit_cast(unsigned int, r);
}

// ---------------- Kernel 1: fused prep GEMM (unchanged from R1) --------------
__global__ __launch_bounds__(256) void gemm_fused(
    const float* __restrict__ X, const float* __restrict__ W1,
    const float* __restrict__ b1, const float* __restrict__ W2,
    _Float16* __restrict__ Pxs2, _Float16* __restrict__ Pxe,
    _Float16* __restrict__ Bfrag2)
{
    const int tid = threadIdx.x;

    if (blockIdx.x >= 768) {                     // W2 repack (16 blocks)
        int base = (blockIdx.x - 768) * 768 + tid;
        #pragma unroll
        for (int r = 0; r < 3; ++r) {
            int idx = base + r * 256;            // < 12288
            int u = idx & 7;
            int lane = (idx >> 3) & 63;
            int kb = idx >> 9;
            int k = kb * 32 + ((lane >> 4) << 3) + u;
            int nn = lane & 15;
            float v = (nn < NL) ? W2[(size_t)k * NL + nn] : 0.f;
            Bfrag2[idx] = (_Float16)v;
        }
        return;
    }

    __shared__ _Float16 As[2][32][72];           // [buf][m][k-local]
    __shared__ _Float16 Bs[2][64][72];           // [buf][n][k-local]

    const int w = tid >> 6, lane = tid & 63;
    const int ln = lane & 15, quad = lane >> 4;
    const int bm = blockIdx.x & 31;
    const int bn = blockIdx.x >> 5;
    const int m0 = bm * 32;
    const int n0g = bn * 64;
    const bool isE = (n0g >= H);
    const float* Wb = W1 + (isE ? (size_t)H * H : 0);
    const int c0 = isE ? (n0g - H) : n0g;

    const int ar = tid >> 4;                     // 0..15
    const int ac = (tid & 15) * 4;

    float4 fA0, fA1, fB0a, fB0b, fB1a, fB1b;

#define G_LOAD(KR) do { \
    const int k0_ = (KR) * 64; \
    fA0 = *(const float4*)&X[(size_t)(m0 + ar) * H + k0_ + ac]; \
    fA1 = *(const float4*)&X[(size_t)(m0 + 16 + ar) * H + k0_ + ac]; \
    const float* wr0_ = &Wb[(size_t)(k0_ + 2 * ar) * H + c0 + ac]; \
    fB0a = *(const float4*)wr0_; \
    fB0b = *(const float4*)(wr0_ + H); \
    const float* wr1_ = &Wb[(size_t)(k0_ + 2 * (16 + ar)) * H + c0 + ac]; \
    fB1a = *(const float4*)wr1_; \
    fB1b = *(const float4*)(wr1_ + H); \
} while (0)

#define L_STORE(BUF) do { \
    h4 oa0 = { (_Float16)fA0.x, (_Float16)fA0.y, (_Float16)fA0.z, (_Float16)fA0.w }; \
    h4 oa1 = { (_Float16)fA1.x, (_Float16)fA1.y, (_Float16)fA1.z, (_Float16)fA1.w }; \
    *(h4*)&As[BUF][ar][ac] = oa0; \
    *(h4*)&As[BUF][16 + ar][ac] = oa1; \
    h2 p0 = {(_Float16)fB0a.x, (_Float16)fB0b.x}; \
    h2 p1 = {(_Float16)fB0a.y, (_Float16)fB0b.y}; \
    h2 p2 = {(_Float16)fB0a.z, (_Float16)fB0b.z}; \
    h2 p3 = {(_Float16)fB0a.w, (_Float16)fB0b.w}; \
    *(h2*)&Bs[BUF][ac + 0][2 * ar] = p0; \
    *(h2*)&Bs[BUF][ac + 1][2 * ar] = p1; \
    *(h2*)&Bs[BUF][ac + 2][2 * ar] = p2; \
    *(h2*)&Bs[BUF][ac + 3][2 * ar] = p3; \
    h2 q0 = {(_Float16)fB1a.x, (_Float16)fB1b.x}; \
    h2 q1 = {(_Float16)fB1a.y, (_Float16)fB1b.y}; \
    h2 q2 = {(_Float16)fB1a.z, (_Float16)fB1b.z}; \
    h2 q3 = {(_Float16)fB1a.w, (_Float16)fB1b.w}; \
    *(h2*)&Bs[BUF][ac + 0][2 * (16 + ar)] = q0; \
    *(h2*)&Bs[BUF][ac + 1][2 * (16 + ar)] = q1; \
    *(h2*)&Bs[BUF][ac + 2][2 * (16 + ar)] = q2; \
    *(h2*)&Bs[BUF][ac + 3][2 * (16 + ar)] = q3; \
} while (0)

    const int wm = w & 1, wn = w >> 1;           // wave tile: 16m x 32n
    f32x4 acc[2] = {};

    G_LOAD(0);
    L_STORE(0);
    __syncthreads();

    for (int kr = 0; kr < 12; ++kr) {
        const int cur = kr & 1;
        if (kr < 11) G_LOAD(kr + 1);
        #pragma unroll
        for (int sub = 0; sub < 2; ++sub) {
            const int ko = sub * 32 + quad * 8;
            half8 a   = *(const half8*)&As[cur][wm * 16 + ln][ko];
            half8 b0  = *(const half8*)&Bs[cur][wn * 32 + ln][ko];
            half8 b1f = *(const half8*)&Bs[cur][wn * 32 + 16 + ln][ko];
            acc[0] = __builtin_amdgcn_mfma_f32_16x16x32_f16(a, b0,  acc[0], 0, 0, 0);
            acc[1] = __builtin_amdgcn_mfma_f32_16x16x32_f16(a, b1f, acc[1], 0, 0, 0);
        }
        if (kr < 11) L_STORE(cur ^ 1);
        __syncthreads();
    }

    const int mb = m0 + wm * 16 + quad * 4;
    const int nb = wn * 32;
    if (!isE) {
        float bv0 = b1[n0g + nb + ln];
        float bv1 = b1[n0g + nb + 16 + ln];
        #pragma unroll
        for (int r = 0; r < 4; ++r) {
            Pxs2[(size_t)(mb + r) * H + (n0g + nb + ln)]      = (_Float16)(acc[0][r] + bv0);
            Pxs2[(size_t)(mb + r) * H + (n0g + nb + 16 + ln)] = (_Float16)(acc[1][r] + bv1);
        }
    } else {
        #pragma unroll
        for (int r = 0; r < 4; ++r) {
            Pxe[(size_t)(mb + r) * H + (c0 + nb + ln)]      = (_Float16)acc[0][r];
            Pxe[(size_t)(mb + r) * H + (c0 + nb + 16 + ln)] = (_Float16)acc[1][r];
        }
    }
#undef G_LOAD
#undef L_STORE
}

// ---------------- Kernel 2: span v7 ------------------------------------------
// R0-v5 structure (grid 1024, no K-split — occupancy proved irrelevant at
// fixed instruction count) + asm-pinned GELU + laundered constants + bfrag
// distance-2 prefetch + constant-trip-count loop with unroll 4 (rotation moves
// eliminated by renaming).
__global__ __launch_bounds__(256, 4) void span_mfma_kernel(
    const _Float16* __restrict__ Pxs2, const _Float16* __restrict__ Pxe,
    const _Float16* __restrict__ Bfrag2, const float* __restrict__ b2,
    float* __restrict__ out)
{
    __shared__ unsigned int xsf[4 * H / 2];   // four i-rows of fp16 pairs (6 KB)
    const int ip = blockIdx.x >> 2;           // 0..255
    const int jq = blockIdx.x & 3;
    const int bi0 = ip * 4;                   // b*L + i (quad start; same b)
    const int b = bi0 >> 8;
    const int tid = threadIdx.x;

    const unsigned int* xsrc = (const unsigned int*)(Pxs2 + (size_t)bi0 * H);
    #pragma unroll
    for (int t = 0; t < 6; ++t) xsf[t * 256 + tid] = xsrc[t * 256 + tid];

    const int wave = tid >> 6;
    const int lane = tid & 63;
    const int n = lane & 15;
    const int quad = lane >> 4;
    const int j_load = jq * 64 + wave * 16 + n;       // A-frag row m = lane&15

    const _Float16* xerow = Pxe + (size_t)(b * L + j_load) * H + quad * 8;
    const uint4* bptr = (const uint4*)(Bfrag2 + (size_t)lane * 8);

    // GELU constants: laundered once into VGPRs so they can't be remat'd
    // inside the loop (VOP3P takes no literals -> each use would cost movs).
    unsigned int cLo = h2const(-3.75f), cHi = h2const(3.75f);
    unsigned int cD4 = h2const(2.0333e-5f), cD3 = h2const(-0.00084672f);
    unsigned int cD2 = h2const(0.0140002f), cD1 = h2const(-0.1234557f);
    unsigned int cD0 = h2const(0.7946463f), cHf = h2const(0.5f);
    asm("" : "+v"(cLo), "+v"(cHi), "+v"(cD4), "+v"(cD3),
             "+v"(cD2), "+v"(cD1), "+v"(cD0), "+v"(cHf));

    f32x4 acc[4] = {};
    __syncthreads();

    uint4 xe0 = *(const uint4*)(xerow);               // kb
    uint4 xe1 = *(const uint4*)(xerow + 32);          // kb+1
    uint4 bf0 = bptr[0];
    uint4 bf1 = bptr[64];

    #pragma unroll 4
    for (int kb = 0; kb < H / 32; ++kb) {
        uint4 xecur = xe0;  xe0 = xe1;
        uint4 bfcur = bf0;  bf0 = bf1;
        if (kb < H / 32 - 2) {                         // wave-uniform
            xe1 = *(const uint4*)(xerow + (kb + 2) * 32);
            bf1 = bptr[(kb + 2) * 64];
        }

        half8 bfrag = __builtin_bit_cast(half8, bfcur);
        const int xo = kb * 16 + quad * 4;            // uint index of lane's 8 fp16

        #pragma unroll
        for (int i01 = 0; i01 < 4; ++i01) {
            uint4 xsd = *(const uint4*)&xsf[i01 * (H / 2) + xo];
            unsigned int pk0 = gelu_asm(xsd.x, xecur.x, cLo, cHi, cD4, cD3, cD2, cD1, cD0, cHf);
            unsigned int pk1 = gelu_asm(xsd.y, xecur.y, cLo, cHi, cD4, cD3, cD2, cD1, cD0, cHf);
            unsigned int pk2 = gelu_asm(xsd.z, xecur.z, cLo, cHi, cD4, cD3, cD2, cD1, cD0, cHf);
            unsigned int pk3 = gelu_asm(xsd.w, xecur.w, cLo, cHi, cD4, cD3, cD2, cD1, cD0, cHf);
            uint4 pk4 = {pk0, pk1, pk2, pk3};
            half8 afrag = __builtin_bit_cast(half8, pk4);
            acc[i01] = __builtin_amdgcn_mfma_f32_16x16x32_f16(afrag, bfrag, acc[i01], 0, 0, 0);
        }
    }

    // C/D: col = lane&15 = label n, row = quad*4 + r = j-offset in the m-tile
    if (n < NL) {
        float b2v = b2[n];
        #pragma unroll
        for (int i01 = 0; i01 < 4; ++i01)
            #pragma unroll
            for (int r = 0; r < 4; ++r) {
                int j = jq * 64 + wave * 16 + quad * 4 + r;
                out[((size_t)(bi0 + i01) * L + j) * NL + n] = acc[i01][r] + b2v;
            }
    }
}

// ---------------- Launch ------------------------------------------------------
extern "C" void kernel_launch(void* const* d_in, const int* in_sizes, int n_in,
                              void* d_out, int out_size, void* d_ws, size_t ws_size,
                              hipStream_t stream)
{
    (void)in_sizes; (void)n_in; (void)out_size; (void)ws_size;
    const float* X  = (const float*)d_in[0];
    const float* W1 = (const float*)d_in[1];
    const float* b1 = (const float*)d_in[2];
    const float* W2 = (const float*)d_in[3];
    const float* b2 = (const float*)d_in[4];
    float* out = (float*)d_out;

    char* ws = (char*)d_ws;
    _Float16* Pxs2   = (_Float16*)ws;                          // 1.5 MB
    _Float16* Pxe    = Pxs2 + (size_t)NB * L * H;              // 1.5 MB
    _Float16* Bfrag2 = Pxe + (size_t)NB * L * H;               // 24 KB

    gemm_fused<<<dim3(784), 256, 0, stream>>>(X, W1, b1, W2, Pxs2, Pxe, Bfrag2);
    span_mfma_kernel<<<NB * L, 256, 0, stream>>>(Pxs2, Pxe, Bfrag2, b2, out);
}

// Round 3
// 120.583 us; speedup vs baseline: 1.0258x; 1.0219x over previous
//
#include <hip/hip_runtime.h>
#include <math.h>

#define H 768
#define L 256
#define NB 4
#define NL 13

typedef _Float16 h2 __attribute__((ext_vector_type(2)));
typedef _Float16 h4 __attribute__((ext_vector_type(4)));
typedef _Float16 half8 __attribute__((ext_vector_type(8)));
typedef float f32x4 __attribute__((ext_vector_type(4)));

__device__ inline unsigned int h2const(float f) {
    _Float16 c = (_Float16)f;
    h2 r = {c, c};
    return __builtin_bit_cast(unsigned int, r);
}

// 4-way-interleaved packed-fp16 GELU: one asm block, 40 v_pk ops, four
// independent chains round-robin so every dependency is >=4 issue slots back
// (covers ~8cyc VALU latency with a SINGLE wave; separate asm blocks could
// not be interleaved by the scheduler -> 62% issue efficiency in R2).
// The final x0.5 is FOLDED INTO W2 (repack writes 0.5*W2): 0.5*x is an exact
// exponent shift in fp16, so MFMA products are bit-identical; saves 1 of 11
// pk ops (pk-f16 is half-rate: FP16 vec TF == FP32 TF on MI355X).
__device__ inline void gelu4_asm(
    unsigned int xs0, unsigned int xs1, unsigned int xs2, unsigned int xs3,
    unsigned int xe0, unsigned int xe1, unsigned int xe2, unsigned int xe3,
    unsigned int lo, unsigned int hi,
    unsigned int d4, unsigned int d3, unsigned int d2, unsigned int d1,
    unsigned int d0,
    unsigned int& o0r, unsigned int& o1r, unsigned int& o2r, unsigned int& o3r)
{
    unsigned int o0, o1, o2, o3, c0, c1, c2, c3, u0, u1, u2, u3, p0, p1, p2, p3;
    asm("v_pk_add_f16 %[o0], %[xs0], %[xe0]\n\t"
        "v_pk_add_f16 %[o1], %[xs1], %[xe1]\n\t"
        "v_pk_add_f16 %[o2], %[xs2], %[xe2]\n\t"
        "v_pk_add_f16 %[o3], %[xs3], %[xe3]\n\t"
        "v_pk_max_f16 %[c0], %[o0], %[lo]\n\t"
        "v_pk_max_f16 %[c1], %[o1], %[lo]\n\t"
        "v_pk_max_f16 %[c2], %[o2], %[lo]\n\t"
        "v_pk_max_f16 %[c3], %[o3], %[lo]\n\t"
        "v_pk_min_f16 %[c0], %[c0], %[hi]\n\t"
        "v_pk_min_f16 %[c1], %[c1], %[hi]\n\t"
        "v_pk_min_f16 %[c2], %[c2], %[hi]\n\t"
        "v_pk_min_f16 %[c3], %[c3], %[hi]\n\t"
        "v_pk_mul_f16 %[u0], %[c0], %[c0]\n\t"
        "v_pk_mul_f16 %[u1], %[c1], %[c1]\n\t"
        "v_pk_mul_f16 %[u2], %[c2], %[c2]\n\t"
        "v_pk_mul_f16 %[u3], %[c3], %[c3]\n\t"
        "v_pk_fma_f16 %[p0], %[u0], %[d4], %[d3]\n\t"
        "v_pk_fma_f16 %[p1], %[u1], %[d4], %[d3]\n\t"
        "v_pk_fma_f16 %[p2], %[u2], %[d4], %[d3]\n\t"
        "v_pk_fma_f16 %[p3], %[u3], %[d4], %[d3]\n\t"
        "v_pk_fma_f16 %[p0], %[u0], %[p0], %[d2]\n\t"
        "v_pk_fma_f16 %[p1], %[u1], %[p1], %[d2]\n\t"
        "v_pk_fma_f16 %[p2], %[u2], %[p2], %[d2]\n\t"
        "v_pk_fma_f16 %[p3], %[u3], %[p3], %[d2]\n\t"
        "v_pk_fma_f16 %[p0], %[u0], %[p0], %[d1]\n\t"
        "v_pk_fma_f16 %[p1], %[u1], %[p1], %[d1]\n\t"
        "v_pk_fma_f16 %[p2], %[u2], %[p2], %[d1]\n\t"
        "v_pk_fma_f16 %[p3], %[u3], %[p3], %[d1]\n\t"
        "v_pk_fma_f16 %[p0], %[u0], %[p0], %[d0]\n\t"
        "v_pk_fma_f16 %[p1], %[u1], %[p1], %[d0]\n\t"
        "v_pk_fma_f16 %[p2], %[u2], %[p2], %[d0]\n\t"
        "v_pk_fma_f16 %[p3], %[u3], %[p3], %[d0]\n\t"
        "v_pk_mul_f16 %[p0], %[c0], %[p0]\n\t"
        "v_pk_mul_f16 %[p1], %[c1], %[p1]\n\t"
        "v_pk_mul_f16 %[p2], %[c2], %[p2]\n\t"
        "v_pk_mul_f16 %[p3], %[c3], %[p3]\n\t"
        "v_pk_fma_f16 %[o0], %[o0], %[p0], %[o0]\n\t"
        "v_pk_fma_f16 %[o1], %[o1], %[p1], %[o1]\n\t"
        "v_pk_fma_f16 %[o2], %[o2], %[p2], %[o2]\n\t"
        "v_pk_fma_f16 %[o3], %[o3], %[p3], %[o3]"
        : [o0]"=&v"(o0), [o1]"=&v"(o1), [o2]"=&v"(o2), [o3]"=&v"(o3),
          [c0]"=&v"(c0), [c1]"=&v"(c1), [c2]"=&v"(c2), [c3]"=&v"(c3),
          [u0]"=&v"(u0), [u1]"=&v"(u1), [u2]"=&v"(u2), [u3]"=&v"(u3),
          [p0]"=&v"(p0), [p1]"=&v"(p1), [p2]"=&v"(p2), [p3]"=&v"(p3)
        : [xs0]"v"(xs0), [xs1]"v"(xs1), [xs2]"v"(xs2), [xs3]"v"(xs3),
          [xe0]"v"(xe0), [xe1]"v"(xe1), [xe2]"v"(xe2), [xe3]"v"(xe3),
          [lo]"v"(lo), [hi]"v"(hi), [d4]"v"(d4), [d3]"v"(d3),
          [d2]"v"(d2), [d1]"v"(d1), [d0]"v"(d0));
    o0r = o0; o1r = o1; o2r = o2; o3r = o3;
}

// ---------------- Kernel 1: fused prep GEMM (repack now halves W2) -----------
__global__ __launch_bounds__(256) void gemm_fused(
    const float* __restrict__ X, const float* __restrict__ W1,
    const float* __restrict__ b1, const float* __restrict__ W2,
    _Float16* __restrict__ Pxs2, _Float16* __restrict__ Pxe,
    _Float16* __restrict__ Bfrag2)
{
    const int tid = threadIdx.x;

    if (blockIdx.x >= 768) {                     // W2 repack (16 blocks)
        int base = (blockIdx.x - 768) * 768 + tid;
        #pragma unroll
        for (int r = 0; r < 3; ++r) {
            int idx = base + r * 256;            // < 12288
            int u = idx & 7;
            int lane = (idx >> 3) & 63;
            int kb = idx >> 9;
            int k = kb * 32 + ((lane >> 4) << 3) + u;
            int nn = lane & 15;
            float v = (nn < NL) ? W2[(size_t)k * NL + nn] : 0.f;
            Bfrag2[idx] = (_Float16)(0.5f * v);  // GELU's x0.5 folded here
        }
        return;
    }

    __shared__ _Float16 As[2][32][72];           // [buf][m][k-local]
    __shared__ _Float16 Bs[2][64][72];           // [buf][n][k-local]

    const int w = tid >> 6, lane = tid & 63;
    const int ln = lane & 15, quad = lane >> 4;
    const int bm = blockIdx.x & 31;
    const int bn = blockIdx.x >> 5;
    const int m0 = bm * 32;
    const int n0g = bn * 64;
    const bool isE = (n0g >= H);
    const float* Wb = W1 + (isE ? (size_t)H * H : 0);
    const int c0 = isE ? (n0g - H) : n0g;

    const int ar = tid >> 4;                     // 0..15
    const int ac = (tid & 15) * 4;

    float4 fA0, fA1, fB0a, fB0b, fB1a, fB1b;

#define G_LOAD(KR) do { \
    const int k0_ = (KR) * 64; \
    fA0 = *(const float4*)&X[(size_t)(m0 + ar) * H + k0_ + ac]; \
    fA1 = *(const float4*)&X[(size_t)(m0 + 16 + ar) * H + k0_ + ac]; \
    const float* wr0_ = &Wb[(size_t)(k0_ + 2 * ar) * H + c0 + ac]; \
    fB0a = *(const float4*)wr0_; \
    fB0b = *(const float4*)(wr0_ + H); \
    const float* wr1_ = &Wb[(size_t)(k0_ + 2 * (16 + ar)) * H + c0 + ac]; \
    fB1a = *(const float4*)wr1_; \
    fB1b = *(const float4*)(wr1_ + H); \
} while (0)

#define L_STORE(BUF) do { \
    h4 oa0 = { (_Float16)fA0.x, (_Float16)fA0.y, (_Float16)fA0.z, (_Float16)fA0.w }; \
    h4 oa1 = { (_Float16)fA1.x, (_Float16)fA1.y, (_Float16)fA1.z, (_Float16)fA1.w }; \
    *(h4*)&As[BUF][ar][ac] = oa0; \
    *(h4*)&As[BUF][16 + ar][ac] = oa1; \
    h2 p0 = {(_Float16)fB0a.x, (_Float16)fB0b.x}; \
    h2 p1 = {(_Float16)fB0a.y, (_Float16)fB0b.y}; \
    h2 p2 = {(_Float16)fB0a.z, (_Float16)fB0b.z}; \
    h2 p3 = {(_Float16)fB0a.w, (_Float16)fB0b.w}; \
    *(h2*)&Bs[BUF][ac + 0][2 * ar] = p0; \
    *(h2*)&Bs[BUF][ac + 1][2 * ar] = p1; \
    *(h2*)&Bs[BUF][ac + 2][2 * ar] = p2; \
    *(h2*)&Bs[BUF][ac + 3][2 * ar] = p3; \
    h2 q0 = {(_Float16)fB1a.x, (_Float16)fB1b.x}; \
    h2 q1 = {(_Float16)fB1a.y, (_Float16)fB1b.y}; \
    h2 q2 = {(_Float16)fB1a.z, (_Float16)fB1b.z}; \
    h2 q3 = {(_Float16)fB1a.w, (_Float16)fB1b.w}; \
    *(h2*)&Bs[BUF][ac + 0][2 * (16 + ar)] = q0; \
    *(h2*)&Bs[BUF][ac + 1][2 * (16 + ar)] = q1; \
    *(h2*)&Bs[BUF][ac + 2][2 * (16 + ar)] = q2; \
    *(h2*)&Bs[BUF][ac + 3][2 * (16 + ar)] = q3; \
} while (0)

    const int wm = w & 1, wn = w >> 1;           // wave tile: 16m x 32n
    f32x4 acc[2] = {};

    G_LOAD(0);
    L_STORE(0);
    __syncthreads();

    for (int kr = 0; kr < 12; ++kr) {
        const int cur = kr & 1;
        if (kr < 11) G_LOAD(kr + 1);
        #pragma unroll
        for (int sub = 0; sub < 2; ++sub) {
            const int ko = sub * 32 + quad * 8;
            half8 a   = *(const half8*)&As[cur][wm * 16 + ln][ko];
            half8 b0  = *(const half8*)&Bs[cur][wn * 32 + ln][ko];
            half8 b1f = *(const half8*)&Bs[cur][wn * 32 + 16 + ln][ko];
            acc[0] = __builtin_amdgcn_mfma_f32_16x16x32_f16(a, b0,  acc[0], 0, 0, 0);
            acc[1] = __builtin_amdgcn_mfma_f32_16x16x32_f16(a, b1f, acc[1], 0, 0, 0);
        }
        if (kr < 11) L_STORE(cur ^ 1);
        __syncthreads();
    }

    const int mb = m0 + wm * 16 + quad * 4;
    const int nb = wn * 32;
    if (!isE) {
        float bv0 = b1[n0g + nb + ln];
        float bv1 = b1[n0g + nb + 16 + ln];
        #pragma unroll
        for (int r = 0; r < 4; ++r) {
            Pxs2[(size_t)(mb + r) * H + (n0g + nb + ln)]      = (_Float16)(acc[0][r] + bv0);
            Pxs2[(size_t)(mb + r) * H + (n0g + nb + 16 + ln)] = (_Float16)(acc[1][r] + bv1);
        }
    } else {
        #pragma unroll
        for (int r = 0; r < 4; ++r) {
            Pxe[(size_t)(mb + r) * H + (c0 + nb + ln)]      = (_Float16)acc[0][r];
            Pxe[(size_t)(mb + r) * H + (c0 + nb + 16 + ln)] = (_Float16)acc[1][r];
        }
    }
#undef G_LOAD
#undef L_STORE
}

// ---------------- Kernel 2: span v8 ------------------------------------------
// Same structure as v7 (grid 1024) but: single interleaved 40-op GELU asm
// block per i01 (4 chains, full intra-wave ILP), x0.5 folded into W2 (10 vs
// 11 pk ops), one-ahead ds_read pipeline for the xs fragment.
__global__ __launch_bounds__(256, 4) void span_mfma_kernel(
    const _Float16* __restrict__ Pxs2, const _Float16* __restrict__ Pxe,
    const _Float16* __restrict__ Bfrag2, const float* __restrict__ b2,
    float* __restrict__ out)
{
    __shared__ unsigned int xsf[4 * H / 2];   // four i-rows of fp16 pairs (6 KB)
    const int ip = blockIdx.x >> 2;           // 0..255
    const int jq = blockIdx.x & 3;
    const int bi0 = ip * 4;                   // b*L + i (quad start; same b)
    const int b = bi0 >> 8;
    const int tid = threadIdx.x;

    const unsigned int* xsrc = (const unsigned int*)(Pxs2 + (size_t)bi0 * H);
    #pragma unroll
    for (int t = 0; t < 6; ++t) xsf[t * 256 + tid] = xsrc[t * 256 + tid];

    const int wave = tid >> 6;
    const int lane = tid & 63;
    const int n = lane & 15;
    const int quad = lane >> 4;
    const int j_load = jq * 64 + wave * 16 + n;       // A-frag row m = lane&15

    const _Float16* xerow = Pxe + (size_t)(b * L + j_load) * H + quad * 8;
    const uint4* bptr = (const uint4*)(Bfrag2 + (size_t)lane * 8);

    // GELU constants laundered once into VGPRs (VOP3P takes no literals).
    unsigned int cLo = h2const(-3.75f), cHi = h2const(3.75f);
    unsigned int cD4 = h2const(2.0333e-5f), cD3 = h2const(-0.00084672f);
    unsigned int cD2 = h2const(0.0140002f), cD1 = h2const(-0.1234557f);
    unsigned int cD0 = h2const(0.7946463f);
    asm("" : "+v"(cLo), "+v"(cHi), "+v"(cD4), "+v"(cD3),
             "+v"(cD2), "+v"(cD1), "+v"(cD0));

    f32x4 acc[4] = {};
    __syncthreads();

    uint4 xe0 = *(const uint4*)(xerow);               // kb
    uint4 xe1 = *(const uint4*)(xerow + 32);          // kb+1
    uint4 bf0 = bptr[0];
    uint4 bf1 = bptr[64];

    #pragma unroll 4
    for (int kb = 0; kb < H / 32; ++kb) {
        uint4 xecur = xe0;  xe0 = xe1;
        uint4 bfcur = bf0;  bf0 = bf1;
        if (kb < H / 32 - 2) {                         // wave-uniform
            xe1 = *(const uint4*)(xerow + (kb + 2) * 32);
            bf1 = bptr[(kb + 2) * 64];
        }

        half8 bfrag = __builtin_bit_cast(half8, bfcur);
        const int xo = kb * 16 + quad * 4;            // uint index of lane's 8 fp16

        uint4 xcur = *(const uint4*)&xsf[0 * (H / 2) + xo];
        #pragma unroll
        for (int i01 = 0; i01 < 4; ++i01) {
            uint4 xnext = xcur;
            if (i01 < 3)                               // one-ahead ds_read
                xnext = *(const uint4*)&xsf[(i01 + 1) * (H / 2) + xo];
            unsigned int pk0, pk1, pk2, pk3;
            gelu4_asm(xcur.x, xcur.y, xcur.z, xcur.w,
                      xecur.x, xecur.y, xecur.z, xecur.w,
                      cLo, cHi, cD4, cD3, cD2, cD1, cD0,
                      pk0, pk1, pk2, pk3);
            uint4 pk4 = {pk0, pk1, pk2, pk3};
            half8 afrag = __builtin_bit_cast(half8, pk4);
            acc[i01] = __builtin_amdgcn_mfma_f32_16x16x32_f16(afrag, bfrag, acc[i01], 0, 0, 0);
            xcur = xnext;
        }
    }

    // C/D: col = lane&15 = label n, row = quad*4 + r = j-offset in the m-tile
    if (n < NL) {
        float b2v = b2[n];
        #pragma unroll
        for (int i01 = 0; i01 < 4; ++i01)
            #pragma unroll
            for (int r = 0; r < 4; ++r) {
                int j = jq * 64 + wave * 16 + quad * 4 + r;
                out[((size_t)(bi0 + i01) * L + j) * NL + n] = acc[i01][r] + b2v;
            }
    }
}

// ---------------- Launch ------------------------------------------------------
extern "C" void kernel_launch(void* const* d_in, const int* in_sizes, int n_in,
                              void* d_out, int out_size, void* d_ws, size_t ws_size,
                              hipStream_t stream)
{
    (void)in_sizes; (void)n_in; (void)out_size; (void)ws_size;
    const float* X  = (const float*)d_in[0];
    const float* W1 = (const float*)d_in[1];
    const float* b1 = (const float*)d_in[2];
    const float* W2 = (const float*)d_in[3];
    const float* b2 = (const float*)d_in[4];
    float* out = (float*)d_out;

    char* ws = (char*)d_ws;
    _Float16* Pxs2   = (_Float16*)ws;                          // 1.5 MB
    _Float16* Pxe    = Pxs2 + (size_t)NB * L * H;              // 1.5 MB
    _Float16* Bfrag2 = Pxe + (size_t)NB * L * H;               // 24 KB

    gemm_fused<<<dim3(784), 256, 0, stream>>>(X, W1, b1, W2, Pxs2, Pxe, Bfrag2);
    span_mfma_kernel<<<NB * L, 256, 0, stream>>>(Pxs2, Pxe, Bfrag2, b2, out);
}

// Round 4
// 119.341 us; speedup vs baseline: 1.0365x; 1.0104x over previous
//
#include <hip/hip_runtime.h>
#include <math.h>

#define H 768
#define L 256
#define NB 4
#define NL 13

typedef _Float16 h2 __attribute__((ext_vector_type(2)));
typedef _Float16 h4 __attribute__((ext_vector_type(4)));
typedef _Float16 half8 __attribute__((ext_vector_type(8)));
typedef float f32x4 __attribute__((ext_vector_type(4)));

__device__ inline unsigned int h2const(float f) {
    _Float16 c = (_Float16)f;
    h2 r = {c, c};
    return __builtin_bit_cast(unsigned int, r);
}

// 4-way-interleaved packed-fp16 GELU: one asm block, 40 v_pk ops, four
// independent chains round-robin. v_pk_*_f16 = 4 cyc VALU occupancy on the
// SIMD-32 (128 element-lanes / 32 wide) -> this block IS the kernel's floor:
// 15.7M pk ops * 4cyc / 1024 SIMD = 25.6 us. The x0.5 is folded into W2.
__device__ inline void gelu4_asm(
    unsigned int xs0, unsigned int xs1, unsigned int xs2, unsigned int xs3,
    unsigned int xe0, unsigned int xe1, unsigned int xe2, unsigned int xe3,
    unsigned int lo, unsigned int hi,
    unsigned int d4, unsigned int d3, unsigned int d2, unsigned int d1,
    unsigned int d0,
    unsigned int& o0r, unsigned int& o1r, unsigned int& o2r, unsigned int& o3r)
{
    unsigned int o0, o1, o2, o3, c0, c1, c2, c3, u0, u1, u2, u3, p0, p1, p2, p3;
    asm("v_pk_add_f16 %[o0], %[xs0], %[xe0]\n\t"
        "v_pk_add_f16 %[o1], %[xs1], %[xe1]\n\t"
        "v_pk_add_f16 %[o2], %[xs2], %[xe2]\n\t"
        "v_pk_add_f16 %[o3], %[xs3], %[xe3]\n\t"
        "v_pk_max_f16 %[c0], %[o0], %[lo]\n\t"
        "v_pk_max_f16 %[c1], %[o1], %[lo]\n\t"
        "v_pk_max_f16 %[c2], %[o2], %[lo]\n\t"
        "v_pk_max_f16 %[c3], %[o3], %[lo]\n\t"
        "v_pk_min_f16 %[c0], %[c0], %[hi]\n\t"
        "v_pk_min_f16 %[c1], %[c1], %[hi]\n\t"
        "v_pk_min_f16 %[c2], %[c2], %[hi]\n\t"
        "v_pk_min_f16 %[c3], %[c3], %[hi]\n\t"
        "v_pk_mul_f16 %[u0], %[c0], %[c0]\n\t"
        "v_pk_mul_f16 %[u1], %[c1], %[c1]\n\t"
        "v_pk_mul_f16 %[u2], %[c2], %[c2]\n\t"
        "v_pk_mul_f16 %[u3], %[c3], %[c3]\n\t"
        "v_pk_fma_f16 %[p0], %[u0], %[d4], %[d3]\n\t"
        "v_pk_fma_f16 %[p1], %[u1], %[d4], %[d3]\n\t"
        "v_pk_fma_f16 %[p2], %[u2], %[d4], %[d3]\n\t"
        "v_pk_fma_f16 %[p3], %[u3], %[d4], %[d3]\n\t"
        "v_pk_fma_f16 %[p0], %[u0], %[p0], %[d2]\n\t"
        "v_pk_fma_f16 %[p1], %[u1], %[p1], %[d2]\n\t"
        "v_pk_fma_f16 %[p2], %[u2], %[p2], %[d2]\n\t"
        "v_pk_fma_f16 %[p3], %[u3], %[p3], %[d2]\n\t"
        "v_pk_fma_f16 %[p0], %[u0], %[p0], %[d1]\n\t"
        "v_pk_fma_f16 %[p1], %[u1], %[p1], %[d1]\n\t"
        "v_pk_fma_f16 %[p2], %[u2], %[p2], %[d1]\n\t"
        "v_pk_fma_f16 %[p3], %[u3], %[p3], %[d1]\n\t"
        "v_pk_fma_f16 %[p0], %[u0], %[p0], %[d0]\n\t"
        "v_pk_fma_f16 %[p1], %[u1], %[p1], %[d0]\n\t"
        "v_pk_fma_f16 %[p2], %[u2], %[p2], %[d0]\n\t"
        "v_pk_fma_f16 %[p3], %[u3], %[p3], %[d0]\n\t"
        "v_pk_mul_f16 %[p0], %[c0], %[p0]\n\t"
        "v_pk_mul_f16 %[p1], %[c1], %[p1]\n\t"
        "v_pk_mul_f16 %[p2], %[c2], %[p2]\n\t"
        "v_pk_mul_f16 %[p3], %[c3], %[p3]\n\t"
        "v_pk_fma_f16 %[o0], %[o0], %[p0], %[o0]\n\t"
        "v_pk_fma_f16 %[o1], %[o1], %[p1], %[o1]\n\t"
        "v_pk_fma_f16 %[o2], %[o2], %[p2], %[o2]\n\t"
        "v_pk_fma_f16 %[o3], %[o3], %[p3], %[o3]"
        : [o0]"=&v"(o0), [o1]"=&v"(o1), [o2]"=&v"(o2), [o3]"=&v"(o3),
          [c0]"=&v"(c0), [c1]"=&v"(c1), [c2]"=&v"(c2), [c3]"=&v"(c3),
          [u0]"=&v"(u0), [u1]"=&v"(u1), [u2]"=&v"(u2), [u3]"=&v"(u3),
          [p0]"=&v"(p0), [p1]"=&v"(p1), [p2]"=&v"(p2), [p3]"=&v"(p3)
        : [xs0]"v"(xs0), [xs1]"v"(xs1), [xs2]"v"(xs2), [xs3]"v"(xs3),
          [xe0]"v"(xe0), [xe1]"v"(xe1), [xe2]"v"(xe2), [xe3]"v"(xe3),
          [lo]"v"(lo), [hi]"v"(hi), [d4]"v"(d4), [d3]"v"(d3),
          [d2]"v"(d2), [d1]"v"(d1), [d0]"v"(d0));
    o0r = o0; o1r = o1; o2r = o2; o3r = o3;
}

// ---------------- Kernel 1: fused prep GEMM (unchanged from R3) --------------
__global__ __launch_bounds__(256) void gemm_fused(
    const float* __restrict__ X, const float* __restrict__ W1,
    const float* __restrict__ b1, const float* __restrict__ W2,
    _Float16* __restrict__ Pxs2, _Float16* __restrict__ Pxe,
    _Float16* __restrict__ Bfrag2)
{
    const int tid = threadIdx.x;

    if (blockIdx.x >= 768) {                     // W2 repack (16 blocks)
        int base = (blockIdx.x - 768) * 768 + tid;
        #pragma unroll
        for (int r = 0; r < 3; ++r) {
            int idx = base + r * 256;            // < 12288
            int u = idx & 7;
            int lane = (idx >> 3) & 63;
            int kb = idx >> 9;
            int k = kb * 32 + ((lane >> 4) << 3) + u;
            int nn = lane & 15;
            float v = (nn < NL) ? W2[(size_t)k * NL + nn] : 0.f;
            Bfrag2[idx] = (_Float16)(0.5f * v);  // GELU's x0.5 folded here
        }
        return;
    }

    __shared__ _Float16 As[2][32][72];           // [buf][m][k-local]
    __shared__ _Float16 Bs[2][64][72];           // [buf][n][k-local]

    const int w = tid >> 6, lane = tid & 63;
    const int ln = lane & 15, quad = lane >> 4;
    const int bm = blockIdx.x & 31;
    const int bn = blockIdx.x >> 5;
    const int m0 = bm * 32;
    const int n0g = bn * 64;
    const bool isE = (n0g >= H);
    const float* Wb = W1 + (isE ? (size_t)H * H : 0);
    const int c0 = isE ? (n0g - H) : n0g;

    const int ar = tid >> 4;                     // 0..15
    const int ac = (tid & 15) * 4;

    float4 fA0, fA1, fB0a, fB0b, fB1a, fB1b;

#define G_LOAD(KR) do { \
    const int k0_ = (KR) * 64; \
    fA0 = *(const float4*)&X[(size_t)(m0 + ar) * H + k0_ + ac]; \
    fA1 = *(const float4*)&X[(size_t)(m0 + 16 + ar) * H + k0_ + ac]; \
    const float* wr0_ = &Wb[(size_t)(k0_ + 2 * ar) * H + c0 + ac]; \
    fB0a = *(const float4*)wr0_; \
    fB0b = *(const float4*)(wr0_ + H); \
    const float* wr1_ = &Wb[(size_t)(k0_ + 2 * (16 + ar)) * H + c0 + ac]; \
    fB1a = *(const float4*)wr1_; \
    fB1b = *(const float4*)(wr1_ + H); \
} while (0)

#define L_STORE(BUF) do { \
    h4 oa0 = { (_Float16)fA0.x, (_Float16)fA0.y, (_Float16)fA0.z, (_Float16)fA0.w }; \
    h4 oa1 = { (_Float16)fA1.x, (_Float16)fA1.y, (_Float16)fA1.z, (_Float16)fA1.w }; \
    *(h4*)&As[BUF][ar][ac] = oa0; \
    *(h4*)&As[BUF][16 + ar][ac] = oa1; \
    h2 p0 = {(_Float16)fB0a.x, (_Float16)fB0b.x}; \
    h2 p1 = {(_Float16)fB0a.y, (_Float16)fB0b.y}; \
    h2 p2 = {(_Float16)fB0a.z, (_Float16)fB0b.z}; \
    h2 p3 = {(_Float16)fB0a.w, (_Float16)fB0b.w}; \
    *(h2*)&Bs[BUF][ac + 0][2 * ar] = p0; \
    *(h2*)&Bs[BUF][ac + 1][2 * ar] = p1; \
    *(h2*)&Bs[BUF][ac + 2][2 * ar] = p2; \
    *(h2*)&Bs[BUF][ac + 3][2 * ar] = p3; \
    h2 q0 = {(_Float16)fB1a.x, (_Float16)fB1b.x}; \
    h2 q1 = {(_Float16)fB1a.y, (_Float16)fB1b.y}; \
    h2 q2 = {(_Float16)fB1a.z, (_Float16)fB1b.z}; \
    h2 q3 = {(_Float16)fB1a.w, (_Float16)fB1b.w}; \
    *(h2*)&Bs[BUF][ac + 0][2 * (16 + ar)] = q0; \
    *(h2*)&Bs[BUF][ac + 1][2 * (16 + ar)] = q1; \
    *(h2*)&Bs[BUF][ac + 2][2 * (16 + ar)] = q2; \
    *(h2*)&Bs[BUF][ac + 3][2 * (16 + ar)] = q3; \
} while (0)

    const int wm = w & 1, wn = w >> 1;           // wave tile: 16m x 32n
    f32x4 acc[2] = {};

    G_LOAD(0);
    L_STORE(0);
    __syncthreads();

    for (int kr = 0; kr < 12; ++kr) {
        const int cur = kr & 1;
        if (kr < 11) G_LOAD(kr + 1);
        #pragma unroll
        for (int sub = 0; sub < 2; ++sub) {
            const int ko = sub * 32 + quad * 8;
            half8 a   = *(const half8*)&As[cur][wm * 16 + ln][ko];
            half8 b0  = *(const half8*)&Bs[cur][wn * 32 + ln][ko];
            half8 b1f = *(const half8*)&Bs[cur][wn * 32 + 16 + ln][ko];
            acc[0] = __builtin_amdgcn_mfma_f32_16x16x32_f16(a, b0,  acc[0], 0, 0, 0);
            acc[1] = __builtin_amdgcn_mfma_f32_16x16x32_f16(a, b1f, acc[1], 0, 0, 0);
        }
        if (kr < 11) L_STORE(cur ^ 1);
        __syncthreads();
    }

    const int mb = m0 + wm * 16 + quad * 4;
    const int nb = wn * 32;
    if (!isE) {
        float bv0 = b1[n0g + nb + ln];
        float bv1 = b1[n0g + nb + 16 + ln];
        #pragma unroll
        for (int r = 0; r < 4; ++r) {
            Pxs2[(size_t)(mb + r) * H + (n0g + nb + ln)]      = (_Float16)(acc[0][r] + bv0);
            Pxs2[(size_t)(mb + r) * H + (n0g + nb + 16 + ln)] = (_Float16)(acc[1][r] + bv1);
        }
    } else {
        #pragma unroll
        for (int r = 0; r < 4; ++r) {
            Pxe[(size_t)(mb + r) * H + (c0 + nb + ln)]      = (_Float16)acc[0][r];
            Pxe[(size_t)(mb + r) * H + (c0 + nb + 16 + ln)] = (_Float16)acc[1][r];
        }
    }
#undef G_LOAD
#undef L_STORE
}

// ---------------- Kernel 2: span v9 ------------------------------------------
// v8 + full-kb-ahead LDS pipeline: all four xsd fragments of kb+1 are
// ds_read at the top of kb's body (first use ~640 busy-cycles later, vs the
// i01=0 fragment previously loaded cold right before use -> ~120-200 cyc
// exposed LDS latency per kb, the main component of the measured 18 us
// occupancy-insensitive idle term). Unroll 2 matches the distance-2 xe/bf
// rotation and keeps renaming pressure under the 128-VGPR/4-wave cap.
__global__ __launch_bounds__(256, 4) void span_mfma_kernel(
    const _Float16* __restrict__ Pxs2, const _Float16* __restrict__ Pxe,
    const _Float16* __restrict__ Bfrag2, const float* __restrict__ b2,
    float* __restrict__ out)
{
    __shared__ unsigned int xsf[4 * H / 2];   // four i-rows of fp16 pairs (6 KB)
    const int ip = blockIdx.x >> 2;           // 0..255
    const int jq = blockIdx.x & 3;
    const int bi0 = ip * 4;                   // b*L + i (quad start; same b)
    const int b = bi0 >> 8;
    const int tid = threadIdx.x;

    const unsigned int* xsrc = (const unsigned int*)(Pxs2 + (size_t)bi0 * H);
    #pragma unroll
    for (int t = 0; t < 6; ++t) xsf[t * 256 + tid] = xsrc[t * 256 + tid];

    const int wave = tid >> 6;
    const int lane = tid & 63;
    const int n = lane & 15;
    const int quad = lane >> 4;
    const int j_load = jq * 64 + wave * 16 + n;       // A-frag row m = lane&15

    const _Float16* xerow = Pxe + (size_t)(b * L + j_load) * H + quad * 8;
    const uint4* bptr = (const uint4*)(Bfrag2 + (size_t)lane * 8);

    // GELU constants laundered once into VGPRs (VOP3P takes no literals).
    unsigned int cLo = h2const(-3.75f), cHi = h2const(3.75f);
    unsigned int cD4 = h2const(2.0333e-5f), cD3 = h2const(-0.00084672f);
    unsigned int cD2 = h2const(0.0140002f), cD1 = h2const(-0.1234557f);
    unsigned int cD0 = h2const(0.7946463f);
    asm("" : "+v"(cLo), "+v"(cHi), "+v"(cD4), "+v"(cD3),
             "+v"(cD2), "+v"(cD1), "+v"(cD0));

    f32x4 acc[4] = {};
    __syncthreads();

    uint4 xe0 = *(const uint4*)(xerow);               // kb
    uint4 xe1 = *(const uint4*)(xerow + 32);          // kb+1
    uint4 bf0 = bptr[0];
    uint4 bf1 = bptr[64];

    // preload ALL FOUR xs fragments of kb=0
    const int xob = quad * 4;
    uint4 xa0 = *(const uint4*)&xsf[0 * (H / 2) + xob];
    uint4 xa1 = *(const uint4*)&xsf[1 * (H / 2) + xob];
    uint4 xa2 = *(const uint4*)&xsf[2 * (H / 2) + xob];
    uint4 xa3 = *(const uint4*)&xsf[3 * (H / 2) + xob];

    #pragma unroll 2
    for (int kb = 0; kb < H / 32; ++kb) {
        uint4 xecur = xe0;  xe0 = xe1;
        uint4 bfcur = bf0;  bf0 = bf1;
        if (kb < H / 32 - 2) {                         // wave-uniform
            xe1 = *(const uint4*)(xerow + (kb + 2) * 32);
            bf1 = bptr[(kb + 2) * 64];
        }

        // issue next-kb ds_reads NOW; results consumed one full kb later
        uint4 nx0 = xa0, nx1 = xa1, nx2 = xa2, nx3 = xa3;
        if (kb < H / 32 - 1) {
            const int xon = (kb + 1) * 16 + quad * 4;
            nx0 = *(const uint4*)&xsf[0 * (H / 2) + xon];
            nx1 = *(const uint4*)&xsf[1 * (H / 2) + xon];
            nx2 = *(const uint4*)&xsf[2 * (H / 2) + xon];
            nx3 = *(const uint4*)&xsf[3 * (H / 2) + xon];
        }

        half8 bfrag = __builtin_bit_cast(half8, bfcur);
        unsigned int pk0, pk1, pk2, pk3;

        gelu4_asm(xa0.x, xa0.y, xa0.z, xa0.w,
                  xecur.x, xecur.y, xecur.z, xecur.w,
                  cLo, cHi, cD4, cD3, cD2, cD1, cD0, pk0, pk1, pk2, pk3);
        { uint4 pk4 = {pk0, pk1, pk2, pk3};
          acc[0] = __builtin_amdgcn_mfma_f32_16x16x32_f16(
                       __builtin_bit_cast(half8, pk4), bfrag, acc[0], 0, 0, 0); }

        gelu4_asm(xa1.x, xa1.y, xa1.z, xa1.w,
                  xecur.x, xecur.y, xecur.z, xecur.w,
                  cLo, cHi, cD4, cD3, cD2, cD1, cD0, pk0, pk1, pk2, pk3);
        { uint4 pk4 = {pk0, pk1, pk2, pk3};
          acc[1] = __builtin_amdgcn_mfma_f32_16x16x32_f16(
                       __builtin_bit_cast(half8, pk4), bfrag, acc[1], 0, 0, 0); }

        gelu4_asm(xa2.x, xa2.y, xa2.z, xa2.w,
                  xecur.x, xecur.y, xecur.z, xecur.w,
                  cLo, cHi, cD4, cD3, cD2, cD1, cD0, pk0, pk1, pk2, pk3);
        { uint4 pk4 = {pk0, pk1, pk2, pk3};
          acc[2] = __builtin_amdgcn_mfma_f32_16x16x32_f16(
                       __builtin_bit_cast(half8, pk4), bfrag, acc[2], 0, 0, 0); }

        gelu4_asm(xa3.x, xa3.y, xa3.z, xa3.w,
                  xecur.x, xecur.y, xecur.z, xecur.w,
                  cLo, cHi, cD4, cD3, cD2, cD1, cD0, pk0, pk1, pk2, pk3);
        { uint4 pk4 = {pk0, pk1, pk2, pk3};
          acc[3] = __builtin_amdgcn_mfma_f32_16x16x32_f16(
                       __builtin_bit_cast(half8, pk4), bfrag, acc[3], 0, 0, 0); }

        xa0 = nx0; xa1 = nx1; xa2 = nx2; xa3 = nx3;
    }

    // C/D: col = lane&15 = label n, row = quad*4 + r = j-offset in the m-tile
    if (n < NL) {
        float b2v = b2[n];
        #pragma unroll
        for (int i01 = 0; i01 < 4; ++i01)
            #pragma unroll
            for (int r = 0; r < 4; ++r) {
                int j = jq * 64 + wave * 16 + quad * 4 + r;
                out[((size_t)(bi0 + i01) * L + j) * NL + n] = acc[i01][r] + b2v;
            }
    }
}

// ---------------- Launch ------------------------------------------------------
extern "C" void kernel_launch(void* const* d_in, const int* in_sizes, int n_in,
                              void* d_out, int out_size, void* d_ws, size_t ws_size,
                              hipStream_t stream)
{
    (void)in_sizes; (void)n_in; (void)out_size; (void)ws_size;
    const float* X  = (const float*)d_in[0];
    const float* W1 = (const float*)d_in[1];
    const float* b1 = (const float*)d_in[2];
    const float* W2 = (const float*)d_in[3];
    const float* b2 = (const float*)d_in[4];
    float* out = (float*)d_out;

    char* ws = (char*)d_ws;
    _Float16* Pxs2   = (_Float16*)ws;                          // 1.5 MB
    _Float16* Pxe    = Pxs2 + (size_t)NB * L * H;              // 1.5 MB
    _Float16* Bfrag2 = Pxe + (size_t)NB * L * H;               // 24 KB

    gemm_fused<<<dim3(784), 256, 0, stream>>>(X, W1, b1, W2, Pxs2, Pxe, Bfrag2);
    span_mfma_kernel<<<NB * L, 256, 0, stream>>>(Pxs2, Pxe, Bfrag2, b2, out);
}